// Round 11
// baseline (215.370 us; speedup 1.0000x reference)
//
#include <hip/hip_runtime.h>
#include <hip/hip_bf16.h>

// Problem constants
#define B_    256
#define CIN   64
#define COUT  64
#define H_    1855
#define K_    6
#define NSTEP 14           // 448 / 32 (K per MFMA)
#define HT    64           // h-tile for transpose kernel
#define NHT   29           // ceil(1855/64)

// conv_main tiling (R4 shape: best measured memory behavior)
#define HT2   32           // h rows per conv tile
#define TPB   58           // tiles per b = ceil(1855/32)
#define NTILE (TPB * B_)   // 14848
#define TPBLK 8            // tiles per block
#define NBLK  (NTILE / TPBLK)   // 1856, % 8 == 0
#define CPX2  (NBLK / 8)        // 232

typedef __bf16 bf16x8 __attribute__((ext_vector_type(8)));
typedef float  f32x4  __attribute__((ext_vector_type(4)));

static __device__ inline unsigned short f2bf(float f) {
    __hip_bfloat16 h = __float2bfloat16(f);
    return *reinterpret_cast<unsigned short*>(&h);
}

// ---------------------------------------------------------------------------
// Kernel 1: pack weights into MFMA A-fragment order (bf16) + 1/total_valid.
// Also zeroes the 128-B zbuf (branch-free source for invalid neighbors).
// ---------------------------------------------------------------------------
__global__ void prep_weights(const float* __restrict__ wc,
                             const float* __restrict__ wn,
                             const int*   __restrict__ nb,
                             unsigned short* __restrict__ W2,
                             float* __restrict__ inv_tv,
                             unsigned short* __restrict__ zbuf) {
    int e = blockIdx.x * 256 + threadIdx.x;     // 0 .. 28671
    int j = e & 7;
    int l = (e >> 3) & 63;
    int t = (e >> 9) & 3;
    int s = e >> 11;
    int o = t * 16 + (l & 15);
    int k = s * 32 + (l >> 4) * 8 + j;
    int slot = k >> 6;
    int c = k & 63;
    float v = (slot == 0) ? wc[o * 64 + c]
                          : wn[(o * 64 + c) * 6 + (slot - 1)];
    W2[e] = f2bf(v);
    if (blockIdx.x == 0 && threadIdx.x < 64) zbuf[threadIdx.x] = 0;
    if (e == 0) {
        int cnt = 1;
        #pragma unroll
        for (int q = 0; q < 6; ++q) cnt += (nb[q] >= 0) ? 1 : 0;
        *inv_tv = 1.0f / (float)cnt;
    }
}

// ---------------------------------------------------------------------------
// Kernel 2: transpose + convert  x (B, C, H) fp32  ->  xT (B, H, C) bf16
// ---------------------------------------------------------------------------
__global__ void transpose_bf16(const float* __restrict__ x,
                               unsigned short* __restrict__ xT) {
    __shared__ __align__(16) unsigned short tile[64][72];  // +8 pad
    int b  = blockIdx.y;
    int h0 = blockIdx.x * HT;
    int t  = threadIdx.x;
    int ho = t & 63;
    int cq = t >> 6;                       // 0..3
    const float* xb = x + (size_t)b * CIN * H_;
    int h = h0 + ho;
    #pragma unroll
    for (int i = 0; i < 16; ++i) {
        int c = i * 4 + cq;
        float v = (h < H_) ? xb[(size_t)c * H_ + h] : 0.f;
        tile[ho][c] = f2bf(v);
    }
    __syncthreads();
    #pragma unroll
    for (int rep = 0; rep < 2; ++rep) {
        int task = rep * 256 + t;          // 0..511  = 64 rows * 8 chunks
        int hh = task >> 3;
        int j  = task & 7;
        int hw = h0 + hh;
        if (hw < H_) {
            *reinterpret_cast<uint4*>(&xT[((size_t)b * H_ + hw) * 64 + j * 8]) =
                *reinterpret_cast<const uint4*>(&tile[hh][j * 8]);
        }
    }
}

// ---------------------------------------------------------------------------
// Kernel 3: R4 pipeline with REG-STAGED gather (T14 issue-early/write-late).
// Rationale: global_load_lds appears to issue per-lane 16-B requests without
// cross-lane merging (64 req/instr); the vector path merges 4 lanes into
// 64-B sectors (16 req/instr). 28 staging instrs/tile * 64 req was the
// schedule-invariant ~6300 cy/tile wall of rounds 2-8.
// Per tile: wave w<7 gathers slot w as 4 per-lane global_load_dwordx4 into
// 16 VGPRs (issued BEFORE compute), then after compute+stores: counted
// vmcnt(8) + 4 swizzled ds_write_b128 (per-cycle conflict-free, layout
// byte-identical to the validated XOR scheme) + lgkm-only barrier.
// ONE barrier per tile; stores never drained in-loop.
// ---------------------------------------------------------------------------
__global__ __launch_bounds__(512, 4) void conv_main(
        const unsigned short* __restrict__ xT,
        const unsigned short* __restrict__ W2,
        const int*   __restrict__ nb,
        const float* __restrict__ bias,
        const float* __restrict__ inv_tv,
        const unsigned short* __restrict__ zbuf,
        float* __restrict__ out) {
    __shared__ __align__(16) unsigned short feat[2][7][HT2][64]; // 57,344 B

    int bid = blockIdx.x;
    int swz   = (bid & 7) * CPX2 + (bid >> 3);   // bijective XCD swizzle
    int gbase = swz * TPBLK;

    int t = threadIdx.x;
    int w = t >> 6;          // wave 0..7
    int l = t & 63;

    // staging lane constants: wave w (<7) owns slot w; lane covers
    // (row = c*8 + lrow, 16-B chunk = lchunk) of that slot.
    int lrow   = l >> 3;
    int lchunk = l & 7;
    bool stg   = (w < 7);
    int q      = w - 1;                 // -1 => center slot

    // compute lane constants (R4-identical)
    int og = w & 3, hh = w >> 2;
    int lr = l & 15, lg = l >> 4;
    int hrow = hh * 16 + lr;            // 0..31
    int sw8  = hrow & 7;

    // W fragments in registers (validated layout)
    const bf16x8* __restrict__ Wf = reinterpret_cast<const bf16x8*>(W2);
    bf16x8 wr[NSTEP];
    #pragma unroll
    for (int s = 0; s < NSTEP; ++s) wr[s] = Wf[(s * 4 + og) * 64 + l];

    float inv = *inv_tv;
    float bv[4];
    #pragma unroll
    for (int r = 0; r < 4; ++r) bv[r] = bias[og * 16 + lg * 4 + r];

    int   nbv[4];        // source rows for the tile gathered next
    uint4 vstg[4];       // gather landing registers (held across compute)

    // ---- prologue: gather+publish tile 0, prefetch rows for tile 1 -------
    {
        int b0  = gbase / TPB;
        int h00 = (gbase - b0 * TPB) * HT2;
        if (stg) {
            #pragma unroll
            for (int c = 0; c < 4; ++c) {
                int h = h00 + c * 8 + lrow;
                int n = (h < H_) ? ((q < 0) ? h : nb[h * 6 + q]) : -1;
                const unsigned short* src = (n >= 0)
                    ? (xT + ((size_t)b0 * H_ + n) * 64 + lchunk * 8)
                    : (zbuf + lchunk * 8);
                vstg[c] = *reinterpret_cast<const uint4*>(src);
            }
            int g1  = gbase + 1;
            int b1  = g1 / TPB;
            int h01 = (g1 - b1 * TPB) * HT2;
            #pragma unroll
            for (int c = 0; c < 4; ++c) {
                int h = h01 + c * 8 + lrow;
                nbv[c] = (h < H_) ? ((q < 0) ? h : nb[h * 6 + q]) : -1;
            }
            #pragma unroll
            for (int c = 0; c < 4; ++c)
                *reinterpret_cast<uint4*>(
                    &feat[0][w][c * 8 + lrow][(lchunk ^ lrow) * 8]) = vstg[c];
        }
        asm volatile("s_waitcnt lgkmcnt(0)" ::: "memory");
        __builtin_amdgcn_s_barrier();
        __builtin_amdgcn_sched_barrier(0);
    }

    // ---- main loop over 8 tiles (fully unrolled) -------------------------
    #pragma unroll
    for (int i = 0; i < TPBLK; ++i) {
        // 1: issue gathers for tile i+1 (vector path, 16 merged req/instr)
        if (i < TPBLK - 1 && stg) {
            int b1 = (gbase + i + 1) / TPB;
            const unsigned short* xb1 = xT + (size_t)b1 * H_ * 64;
            #pragma unroll
            for (int c = 0; c < 4; ++c) {
                int n = nbv[c];
                const unsigned short* src = (n >= 0)
                    ? (xb1 + (size_t)n * 64 + lchunk * 8)
                    : (zbuf + lchunk * 8);
                vstg[c] = *reinterpret_cast<const uint4*>(src);
            }
        }
        __builtin_amdgcn_sched_barrier(0);   // pin issue-early

        // 2: prefetch source rows for tile i+2
        if (i < TPBLK - 2 && stg) {
            int g2  = gbase + i + 2;
            int b2  = g2 / TPB;
            int h02 = (g2 - b2 * TPB) * HT2;
            #pragma unroll
            for (int c = 0; c < 4; ++c) {
                int h = h02 + c * 8 + lrow;
                nbv[c] = (h < H_) ? ((q < 0) ? h : nb[h * 6 + q]) : -1;
            }
        }

        // 3: E — compute tile i from feat[i&1] (14 ds_read_b128 + 14 MFMA)
        int cb = i & 1;
        f32x4 acc = (f32x4){0.f, 0.f, 0.f, 0.f};
        #pragma unroll
        for (int s = 0; s < NSTEP; ++s) {
            int c16 = (((s & 1) * 4 + lg)) ^ sw8;
            bf16x8 bfrag = *reinterpret_cast<const bf16x8*>(
                    &feat[cb][s >> 1][hrow][c16 * 8]);
            acc = __builtin_amdgcn_mfma_f32_16x16x32_bf16(wr[s], bfrag, acc, 0, 0, 0);
        }

        // 4: F — epilogue stores for tile i
        int g    = gbase + i;
        int curb = g / TPB;
        int curh = (g - curb * TPB) * HT2 + hrow;
        if (curh < H_) {
            float* ob = out + (size_t)curb * COUT * H_ + curh;
            #pragma unroll
            for (int r = 0; r < 4; ++r)
                ob[(size_t)(og * 16 + lg * 4 + r) * H_] = acc[r] * inv + bv[r];
        }

        // 5: write-late — wait own gathers, publish to feat[(i+1)&1].
        //    Per-wave FIFO newer-than-gathers: nb(4 if issued) + stores(4).
        //    Predicated loads/stores only make the wait stricter (safe).
        if (i < TPBLK - 1 && stg) {
            if (q >= 0 && i < TPBLK - 2)
                asm volatile("s_waitcnt vmcnt(8)" ::: "memory");
            else
                asm volatile("s_waitcnt vmcnt(4)" ::: "memory");
            __builtin_amdgcn_sched_barrier(0);
            int nbuf = (i + 1) & 1;
            #pragma unroll
            for (int c = 0; c < 4; ++c)
                *reinterpret_cast<uint4*>(
                    &feat[nbuf][w][c * 8 + lrow][(lchunk ^ lrow) * 8]) = vstg[c];
        }

        // 6: single barrier per tile (lgkm only — stores stay in flight)
        if (i < TPBLK - 1) {
            __builtin_amdgcn_sched_barrier(0);
            asm volatile("s_waitcnt lgkmcnt(0)" ::: "memory");
            __builtin_amdgcn_s_barrier();
            __builtin_amdgcn_sched_barrier(0);
        }
    }
}

// ---------------------------------------------------------------------------
extern "C" void kernel_launch(void* const* d_in, const int* in_sizes, int n_in,
                              void* d_out, int out_size, void* d_ws, size_t ws_size,
                              hipStream_t stream) {
    const float* x    = (const float*)d_in[0];
    const int*   nb   = (const int*)  d_in[1];
    const float* wc   = (const float*)d_in[2];
    const float* wn   = (const float*)d_in[3];
    const float* bias = (const float*)d_in[4];
    float* out = (float*)d_out;

    char* ws = (char*)d_ws;
    unsigned short* W2     = (unsigned short*)ws;            // 57,344 B
    float*          inv_tv = (float*)(ws + 57344);           // 4 B
    unsigned short* zbuf   = (unsigned short*)(ws + 57472);  // 128 B zero
    unsigned short* xT     = (unsigned short*)(ws + 57600);  // 60,784,640 B

    prep_weights<<<112, 256, 0, stream>>>(wc, wn, nb, W2, inv_tv, zbuf);

    dim3 tgrid(NHT, B_);
    transpose_bf16<<<tgrid, 256, 0, stream>>>(x, xT);
    conv_main<<<NBLK, 512, 0, stream>>>(xT, W2, nb, bias, inv_tv, zbuf, out);
}

// Round 12
// 212.538 us; speedup vs baseline: 1.0133x; 1.0133x over previous
//
#include <hip/hip_runtime.h>
#include <hip/hip_bf16.h>

// Problem constants
#define B_    256
#define CIN   64
#define COUT  64
#define H_    1855
#define K_    6
#define NSTEP 14           // 448 / 32 (K per MFMA)
#define HT    64           // h-tile for transpose kernel
#define NHT   29           // ceil(1855/64)

// conv_main tiling (R4 shape: best measured memory behavior)
#define HT2   32           // h rows per conv tile
#define TPB   58           // tiles per b = ceil(1855/32)
#define NTILE (TPB * B_)   // 14848
#define TPBLK 8            // tiles per block
#define NBLK  (NTILE / TPBLK)   // 1856, % 8 == 0
#define CPX2  (NBLK / 8)        // 232

typedef __bf16 bf16x8 __attribute__((ext_vector_type(8)));
typedef float  f32x4  __attribute__((ext_vector_type(4)));

static __device__ inline unsigned short f2bf(float f) {
    __hip_bfloat16 h = __float2bfloat16(f);
    return *reinterpret_cast<unsigned short*>(&h);
}

// ---------------------------------------------------------------------------
// Kernel 1: pack weights into MFMA A-fragment order (bf16) + 1/total_valid.
// Also zeroes the 128-B zbuf (branch-free source for invalid neighbors).
// ---------------------------------------------------------------------------
__global__ void prep_weights(const float* __restrict__ wc,
                             const float* __restrict__ wn,
                             const int*   __restrict__ nb,
                             unsigned short* __restrict__ W2,
                             float* __restrict__ inv_tv,
                             unsigned short* __restrict__ zbuf) {
    int e = blockIdx.x * 256 + threadIdx.x;     // 0 .. 28671
    int j = e & 7;
    int l = (e >> 3) & 63;
    int t = (e >> 9) & 3;
    int s = e >> 11;
    int o = t * 16 + (l & 15);
    int k = s * 32 + (l >> 4) * 8 + j;
    int slot = k >> 6;
    int c = k & 63;
    float v = (slot == 0) ? wc[o * 64 + c]
                          : wn[(o * 64 + c) * 6 + (slot - 1)];
    W2[e] = f2bf(v);
    if (blockIdx.x == 0 && threadIdx.x < 64) zbuf[threadIdx.x] = 0;
    if (e == 0) {
        int cnt = 1;
        #pragma unroll
        for (int q = 0; q < 6; ++q) cnt += (nb[q] >= 0) ? 1 : 0;
        *inv_tv = 1.0f / (float)cnt;
    }
}

// ---------------------------------------------------------------------------
// Kernel 2: transpose + convert  x (B, C, H) fp32  ->  xT (B, H, C) bf16
// ---------------------------------------------------------------------------
__global__ void transpose_bf16(const float* __restrict__ x,
                               unsigned short* __restrict__ xT) {
    __shared__ __align__(16) unsigned short tile[64][72];  // +8 pad
    int b  = blockIdx.y;
    int h0 = blockIdx.x * HT;
    int t  = threadIdx.x;
    int ho = t & 63;
    int cq = t >> 6;                       // 0..3
    const float* xb = x + (size_t)b * CIN * H_;
    int h = h0 + ho;
    #pragma unroll
    for (int i = 0; i < 16; ++i) {
        int c = i * 4 + cq;
        float v = (h < H_) ? xb[(size_t)c * H_ + h] : 0.f;
        tile[ho][c] = f2bf(v);
    }
    __syncthreads();
    #pragma unroll
    for (int rep = 0; rep < 2; ++rep) {
        int task = rep * 256 + t;          // 0..511  = 64 rows * 8 chunks
        int hh = task >> 3;
        int j  = task & 7;
        int hw = h0 + hh;
        if (hw < H_) {
            *reinterpret_cast<uint4*>(&xT[((size_t)b * H_ + hw) * 64 + j * 8]) =
                *reinterpret_cast<const uint4*>(&tile[hh][j * 8]);
        }
    }
}

// ---------------------------------------------------------------------------
// Kernel 3: R4 pipeline, reg-staged gather — CLEAN version (vs R11):
// no sched_barrier, no manual waitcnt. The compiler inserts the minimal
// vmcnt before the publish ds_write (vstg register deps) and the
// lgkm/vm drain at __syncthreads.
// Rationale (TA lane-request theory): global_load_lds issues 64 unmerged
// 16-B lane-requests per instr -> 1792/tile, ~1/cy/CU = the invariant
// ~3100 cy/tile wall of R2-R8. Vector loads merge 4 lanes into 64-B
// requests -> 448/tile.
// Layout/read indices byte-identical to R4 (measured conflict-free):
// publish writes LDS[row][chunk ^ (row&7)] from a LINEAR source read.
// ONE barrier per tile (double buffer: publish touches only buf[(i+1)&1],
// whose readers finished before the previous barrier).
// ---------------------------------------------------------------------------
__global__ __launch_bounds__(512, 4) void conv_main(
        const unsigned short* __restrict__ xT,
        const unsigned short* __restrict__ W2,
        const int*   __restrict__ nb,
        const float* __restrict__ bias,
        const float* __restrict__ inv_tv,
        const unsigned short* __restrict__ zbuf,
        float* __restrict__ out) {
    __shared__ __align__(16) unsigned short feat[2][7][HT2][64]; // 57,344 B

    int bid = blockIdx.x;
    int swz   = (bid & 7) * CPX2 + (bid >> 3);   // bijective XCD swizzle
    int gbase = swz * TPBLK;

    int t = threadIdx.x;
    int w = t >> 6;          // wave 0..7
    int l = t & 63;

    // staging lane constants: wave w (<7) owns slot w; lane covers
    // (row = c*8 + lrow, 16-B chunk = lchunk) of that slot. LINEAR source.
    int lrow   = l >> 3;
    int lchunk = l & 7;
    bool stg   = (w < 7);
    int q      = w - 1;                 // -1 => center slot

    // compute lane constants (R4-identical)
    int og = w & 3, hh = w >> 2;
    int lr = l & 15, lg = l >> 4;
    int hrow = hh * 16 + lr;            // 0..31
    int sw8  = hrow & 7;

    // W fragments in registers (validated layout)
    const bf16x8* __restrict__ Wf = reinterpret_cast<const bf16x8*>(W2);
    bf16x8 wr[NSTEP];
    #pragma unroll
    for (int s = 0; s < NSTEP; ++s) wr[s] = Wf[(s * 4 + og) * 64 + l];

    float inv = *inv_tv;
    float bv[4];
    #pragma unroll
    for (int r = 0; r < 4; ++r) bv[r] = bias[og * 16 + lg * 4 + r];

    int   nbv[4];        // source rows for the tile gathered next
    uint4 vstg[4];       // gather landing registers (held across compute)

    // ---- prologue: gather+publish tile 0, prefetch rows for tile 1 -------
    {
        int b0  = gbase / TPB;
        int h00 = (gbase - b0 * TPB) * HT2;
        if (stg) {
            #pragma unroll
            for (int c = 0; c < 4; ++c) {
                int h = h00 + c * 8 + lrow;
                int n = (h < H_) ? ((q < 0) ? h : nb[h * 6 + q]) : -1;
                const unsigned short* src = (n >= 0)
                    ? (xT + ((size_t)b0 * H_ + n) * 64 + lchunk * 8)
                    : (zbuf + lchunk * 8);
                vstg[c] = *reinterpret_cast<const uint4*>(src);
            }
            int g1  = gbase + 1;
            int b1  = g1 / TPB;
            int h01 = (g1 - b1 * TPB) * HT2;
            #pragma unroll
            for (int c = 0; c < 4; ++c) {
                int h = h01 + c * 8 + lrow;
                nbv[c] = (h < H_) ? ((q < 0) ? h : nb[h * 6 + q]) : -1;
            }
            #pragma unroll
            for (int c = 0; c < 4; ++c)
                *reinterpret_cast<uint4*>(
                    &feat[0][w][c * 8 + lrow][(lchunk ^ lrow) * 8]) = vstg[c];
        }
        __syncthreads();
    }

    // ---- main loop over 8 tiles (fully unrolled) -------------------------
    #pragma unroll
    for (int i = 0; i < TPBLK; ++i) {
        // 1: issue gathers for tile i+1 (vector path, 64-B merged requests)
        if (i < TPBLK - 1 && stg) {
            int b1 = (gbase + i + 1) / TPB;
            const unsigned short* xb1 = xT + (size_t)b1 * H_ * 64;
            #pragma unroll
            for (int c = 0; c < 4; ++c) {
                int n = nbv[c];
                const unsigned short* src = (n >= 0)
                    ? (xb1 + (size_t)n * 64 + lchunk * 8)
                    : (zbuf + lchunk * 8);
                vstg[c] = *reinterpret_cast<const uint4*>(src);
            }
        }

        // 2: prefetch source rows for tile i+2
        if (i < TPBLK - 2 && stg) {
            int g2  = gbase + i + 2;
            int b2  = g2 / TPB;
            int h02 = (g2 - b2 * TPB) * HT2;
            #pragma unroll
            for (int c = 0; c < 4; ++c) {
                int h = h02 + c * 8 + lrow;
                nbv[c] = (h < H_) ? ((q < 0) ? h : nb[h * 6 + q]) : -1;
            }
        }

        // 3: E — compute tile i from feat[i&1] (14 ds_read_b128 + 14 MFMA)
        int cb = i & 1;
        f32x4 acc = (f32x4){0.f, 0.f, 0.f, 0.f};
        #pragma unroll
        for (int s = 0; s < NSTEP; ++s) {
            int c16 = (((s & 1) * 4 + lg)) ^ sw8;
            bf16x8 bfrag = *reinterpret_cast<const bf16x8*>(
                    &feat[cb][s >> 1][hrow][c16 * 8]);
            acc = __builtin_amdgcn_mfma_f32_16x16x32_bf16(wr[s], bfrag, acc, 0, 0, 0);
        }

        // 4: F — epilogue stores for tile i
        int g    = gbase + i;
        int curb = g / TPB;
        int curh = (g - curb * TPB) * HT2 + hrow;
        if (curh < H_) {
            float* ob = out + (size_t)curb * COUT * H_ + curh;
            #pragma unroll
            for (int r = 0; r < 4; ++r)
                ob[(size_t)(og * 16 + lg * 4 + r) * H_] = acc[r] * inv + bv[r];
        }

        // 5: publish tile i+1 into feat[(i+1)&1] (compiler waits on vstg)
        if (i < TPBLK - 1 && stg) {
            int nbuf = (i + 1) & 1;
            #pragma unroll
            for (int c = 0; c < 4; ++c)
                *reinterpret_cast<uint4*>(
                    &feat[nbuf][w][c * 8 + lrow][(lchunk ^ lrow) * 8]) = vstg[c];
        }

        // 6: single barrier per tile
        if (i < TPBLK - 1) __syncthreads();
    }
}

// ---------------------------------------------------------------------------
extern "C" void kernel_launch(void* const* d_in, const int* in_sizes, int n_in,
                              void* d_out, int out_size, void* d_ws, size_t ws_size,
                              hipStream_t stream) {
    const float* x    = (const float*)d_in[0];
    const int*   nb   = (const int*)  d_in[1];
    const float* wc   = (const float*)d_in[2];
    const float* wn   = (const float*)d_in[3];
    const float* bias = (const float*)d_in[4];
    float* out = (float*)d_out;

    char* ws = (char*)d_ws;
    unsigned short* W2     = (unsigned short*)ws;            // 57,344 B
    float*          inv_tv = (float*)(ws + 57344);           // 4 B
    unsigned short* zbuf   = (unsigned short*)(ws + 57472);  // 128 B zero
    unsigned short* xT     = (unsigned short*)(ws + 57600);  // 60,784,640 B

    prep_weights<<<112, 256, 0, stream>>>(wc, wn, nb, W2, inv_tv, zbuf);

    dim3 tgrid(NHT, B_);
    transpose_bf16<<<tgrid, 256, 0, stream>>>(x, xT);
    conv_main<<<NBLK, 512, 0, stream>>>(xT, W2, nb, bias, inv_tv, zbuf, out);
}